// Round 10
// baseline (90.221 us; speedup 1.0000x reference)
//
#include <hip/hip_runtime.h>

typedef _Float16 f16;
typedef _Float16 f16x8 __attribute__((ext_vector_type(8)));
typedef _Float16 f16x4 __attribute__((ext_vector_type(4)));
typedef float    f32x4 __attribute__((ext_vector_type(4)));

#define MFMA16(a,b,c) __builtin_amdgcn_mfma_f32_16x16x32_f16((a),(b),(c),0,0,0)
#define AS1(p) ((const __attribute__((address_space(1))) void*)(p))
#define AS3(p) ((__attribute__((address_space(3))) void*)(p))

constexpr int   NH   = 12;
constexpr int   SEQ  = 1024;
constexpr float INV128 = 1.0f/128.0f;
constexpr int   ECAP = 98304;
constexpr float THR_NOT = -4.5948f;   // ln(1/0.99 - 1) rounded toward safe side

__device__ __forceinline__ float q8f(float x){ return rintf(x*128.0f)*INV128; }
__device__ __forceinline__ float q4f(float x){ return rintf(x*8.0f)*0.125f; }

// ---------------- K0: merged prelude ----------------
__global__ __launch_bounds__(256) void prelude(
    const float* __restrict__ x, const float* __restrict__ qkv_w,
    float* __restrict__ out, const float* __restrict__ pb,
    const float* __restrict__ biases, int NU,
    f16* __restrict__ xq, f16* __restrict__ wq,
    float* __restrict__ Bh, int* __restrict__ cnt, int* __restrict__ cnt2)
{
    const int b = blockIdx.x, t = threadIdx.x;
    if (b < 6144){
        int i = (b*256 + t)*4;
        float4 v = *(const float4*)(x + i);
        f16x4 o;
        o[0]=(f16)q8f(v.x); o[1]=(f16)q8f(v.y); o[2]=(f16)q8f(v.z); o[3]=(f16)q8f(v.w);
        *(f16x4*)(xq + i) = o;
    } else if (b < 9600){
        int i = ((b-6144)*256 + t)*4;
        float4 v = *(const float4*)(qkv_w + i);
        f16x4 o;
        o[0]=(f16)q8f(v.x); o[1]=(f16)q8f(v.y); o[2]=(f16)q8f(v.z); o[3]=(f16)q8f(v.w);
        *(f16x4*)(wq + i) = o;
    } else if (b < 15744){
        int i = ((b-9600)*256 + t)*4;
        int c = i % 768;
        float4 v = { pb[c], pb[c+1], pb[c+2], pb[c+3] };
        *(float4*)(out + i) = v;
    } else {
        int h = b - 15744;
        float m = 0.f;
        for (int i = t; i < NU; i += 256) m = fmaxf(m, fabsf(biases[h*NU + i]));
        #pragma unroll
        for (int d=32; d>=1; d>>=1) m = fmaxf(m, __shfl_xor(m, d));
        __shared__ float s[4];
        if ((t&63)==0) s[t>>6] = m;
        __syncthreads();
        if (t==0){
            Bh[h] = fmaxf(fmaxf(s[0],s[1]), fmaxf(s[2],s[3]));
            if (h==0){ *cnt = 0; *cnt2 = 0; }
        }
    }
}

// ---------------- K1: QK-only GEMM, BK=32 x 4-buf x depth-3 prefetch ----------
__global__ __launch_bounds__(256) void gemm_qk(
    const f16* __restrict__ Aq, const f16* __restrict__ Wq,
    const float* __restrict__ g, const float* __restrict__ bb,
    f16* __restrict__ Qm, f16* __restrict__ Km)
{
    __shared__ f16 As[4][128][32];
    __shared__ f16 Bs[4][128][32];
    const int t = threadIdx.x;
    // XCD row-chunk swizzle: xcd = bid&7 owns rows [xcd*8, xcd*8+8) x all heads
    const int d = blockIdx.x;               // 0..767
    const int q = d >> 3;
    const int head = q % 12;
    const int row0 = ((d & 7)*8 + q/12) * 128;
    const int wid = t>>6, lane = t&63;
    const int wr = (wid>>1)*64, wc = (wid&1)*64;
    const int lr = lane&15, lg = lane>>4;

    const f16* Asrc = Aq + (size_t)row0*768;
    const f16* Bsrc = Wq + (size_t)(head*384)*768;

    // staging: wave wid covers rows wid*32..wid*32+31 (2 instrs of 16 rows each)
    const int rbase = wid*32;
    const int lrow  = lane>>2;                      // 0..15
    const int gs    = (lane&3) ^ (lrow&3);          // pre-swizzled source slot
    const int scoff = gs*8;                         // f16 elements

    f32x4 acc[4][4] = {};

#define STAGE(buf, kt) { \
    const int koff = (kt)*32; \
    __builtin_amdgcn_global_load_lds(AS1(Asrc + (size_t)(rbase +      lrow)*768 + koff + scoff), AS3(&As[buf][rbase     ][0]), 16, 0, 0); \
    __builtin_amdgcn_global_load_lds(AS1(Bsrc + (size_t)(rbase +      lrow)*768 + koff + scoff), AS3(&Bs[buf][rbase     ][0]), 16, 0, 0); \
    __builtin_amdgcn_global_load_lds(AS1(Asrc + (size_t)(rbase + 16 + lrow)*768 + koff + scoff), AS3(&As[buf][rbase + 16][0]), 16, 0, 0); \
    __builtin_amdgcn_global_load_lds(AS1(Bsrc + (size_t)(rbase + 16 + lrow)*768 + koff + scoff), AS3(&Bs[buf][rbase + 16][0]), 16, 0, 0); }

    // prologue: tiles 0,1,2
    STAGE(0, 0)
    STAGE(1, 1)
    STAGE(2, 2)

    const int slot = (lg ^ (lr&3))*8;   // swizzled ds_read slot (row&3 == lr&3)

    for (int kt = 0; kt < 24; kt++){
        __builtin_amdgcn_s_barrier();           // WAR: compute(kt-1) done everywhere
        if (kt < 21){
            STAGE((kt+3)&3, kt+3)
            asm volatile("s_waitcnt vmcnt(12)" ::: "memory");   // tile kt complete
        } else if (kt == 21){
            asm volatile("s_waitcnt vmcnt(8)" ::: "memory");
        } else if (kt == 22){
            asm volatile("s_waitcnt vmcnt(4)" ::: "memory");
        } else {
            asm volatile("s_waitcnt vmcnt(0)" ::: "memory");
        }
        __builtin_amdgcn_s_barrier();           // tile kt visible to all waves

        const int b = kt & 3;
        f16x8 af[4], bf[4];
        #pragma unroll
        for (int i=0;i<4;i++){
            af[i] = *(const f16x8*)&As[b][wr + i*16 + lr][slot];
            bf[i] = *(const f16x8*)&Bs[b][wc + i*16 + lr][slot];
        }
        __builtin_amdgcn_s_setprio(1);
        #pragma unroll
        for (int i=0;i<4;i++)
            #pragma unroll
            for (int j=0;j<4;j++)
                acc[i][j] = MFMA16(af[i], bf[j], acc[i][j]);
        __builtin_amdgcn_s_setprio(0);
    }
#undef STAGE

    #pragma unroll
    for (int j=0;j<4;j++){
        int rr = wc + j*16 + lr;
        int gcol = head*384 + rr;
        float gg = g[gcol], bv = bb[gcol];
        #pragma unroll
        for (int i=0;i<4;i++){
            #pragma unroll
            for (int r=0;r<4;r++){
                int grow = row0 + wr + i*16 + lg*4 + r;
                float h = __fadd_rn(__fmul_rn(acc[i][j][r], gg), bv);
                float v4 = q4f(q8f(h));
                int bq = grow >> 10, n = grow & 1023;
                size_t base = ((size_t)(bq*NH + head)*SEQ + n)*64;
                if (rr < 64) Qm[base + rr]      = (f16)v4;
                else         Km[base + rr - 64] = (f16)(v4 * 0.125f);
            }
        }
    }
}

// ---------------- K2: pass A — bias-free max/second-max screen ----------
__global__ __launch_bounds__(256) void pass_a(
    const f16* __restrict__ Qm, const f16* __restrict__ Km,
    const float* __restrict__ Bh,
    int* __restrict__ cnt2, int2* __restrict__ amb)
{
    __shared__ f16 Ks[128][72];

    const int t = threadIdx.x;
    const int bid = blockIdx.x;                 // 0..1535
    const int wg  = (bid & 7)*192 + (bid >> 3);
    const int bh  = wg >> 4;
    const int qt  = wg & 15;
    const int n0 = qt*64;
    const int lane = t&63, w = t>>6;
    const int lr = lane&15, lg = lane>>4;

    const float thr = THR_NOT + 2.0f*Bh[bh % NH] + 1e-4f;

    const f16* qp = &Qm[((size_t)bh*SEQ + n0 + w*16 + lr)*64];
    const f16x8 aq0 = *(const f16x8*)(qp + lg*8);
    const f16x8 aq1 = *(const f16x8*)(qp + 32 + lg*8);

    float mx[4], m2[4];
    #pragma unroll
    for (int r=0;r<4;r++){ mx[r] = -3e38f; m2[r] = -3e38f; }

    for (int kb = 0; kb < SEQ; kb += 128){
        __syncthreads();
        for (int sidx = t; sidx < 1024; sidx += 256){
            int r = sidx>>3, q = (sidx&7)*8;
            *(f16x8*)&Ks[r][q] = *(const f16x8*)&Km[((size_t)bh*SEQ + kb + r)*64 + q];
        }
        __syncthreads();
        #pragma unroll
        for (int ct=0; ct<8; ct++){
            f16x8 b0 = *(const f16x8*)&Ks[ct*16+lr][lg*8];
            f16x8 b1 = *(const f16x8*)&Ks[ct*16+lr][32+lg*8];
            f32x4 c = {};
            c = MFMA16(aq0, b0, c);
            c = MFMA16(aq1, b1, c);
            #pragma unroll
            for (int r=0;r<4;r++){
                float sc = c[r];
                float om = mx[r];
                m2[r] = fmaxf(m2[r], fminf(sc, om));
                mx[r] = fmaxf(om, sc);
            }
        }
    }

    #pragma unroll
    for (int r=0;r<4;r++){
        float mxv = mx[r], m2v = m2[r];
        #pragma unroll
        for (int d=1; d<16; d<<=1){
            float mo  = __shfl_xor(mxv, d);
            float m2o = __shfl_xor(m2v, d);
            float sec = fmaxf(fminf(mxv, mo), (mxv >= mo) ? m2v : m2o);
            mxv = fmaxf(mxv, mo);
            m2v = sec;
        }
        if (lr == 0){
            if (m2v - mxv < thr){
                int n = n0 + w*16 + lg*4 + r;
                int pos = atomicAdd(cnt2, 1);
                if (pos < ECAP) amb[pos] = make_int2((bh<<10) | n, 0);
            }
        }
    }
}

// ---------------- K2b: exact biased resolve (flag + argmax) ----------
__global__ __launch_bounds__(256) void resolve_kernel(
    const f16* __restrict__ Qm, const f16* __restrict__ Km,
    const float* __restrict__ biases, int NU,
    const int* __restrict__ cnt2, const int2* __restrict__ amb,
    int* __restrict__ cnt, int2* __restrict__ entries)
{
    __shared__ float qrow[64];
    __shared__ float rmax[4], rsum[4];
    __shared__ int   rarg[4];
    int total = *cnt2; if (total > ECAP) total = ECAP;
    const int t = threadIdx.x;
    for (int e = blockIdx.x; e < total; e += gridDim.x){
        int2 a = amb[e];
        int bh = a.x>>10, n = a.x&1023, h = bh % NH;
        __syncthreads();
        if (t < 64) qrow[t] = (float)Qm[((size_t)bh*SEQ + n)*64 + t];
        __syncthreads();
        int rn = n>>5, cnn = n&31;
        float lmax = -3e38f; int larg = 0; float lsc[4];
        #pragma unroll
        for (int j=0;j<4;j++){
            int m = t + j*256;
            const f16* kp = &Km[((size_t)bh*SEQ + m)*64];
            float d = 0.f;
            for (int u=0; u<64; u+=8){
                f16x8 kv = *(const f16x8*)(kp+u);
                #pragma unroll
                for (int z=0; z<8; z++) d += qrow[u+z]*(float)kv[z];
            }
            int idx = __builtin_abs(rn-(m>>5))*32 + __builtin_abs(cnn-(m&31));
            lsc[j] = d + biases[h*NU + idx];
            if (lsc[j] > lmax){ lmax = lsc[j]; larg = m; }
        }
        #pragma unroll
        for (int dd=32; dd>=1; dd>>=1){
            float mo = __shfl_xor(lmax, dd);
            int   ao = __shfl_xor(larg, dd);
            if (mo > lmax){ lmax = mo; larg = ao; }
        }
        if ((t&63)==0){ rmax[t>>6] = lmax; rarg[t>>6] = larg; }
        __syncthreads();
        float MX = rmax[0]; int ARG = rarg[0];
        #pragma unroll
        for (int k=1;k<4;k++){ if (rmax[k] > MX){ MX = rmax[k]; ARG = rarg[k]; } }
        float ls = 0.f;
        #pragma unroll
        for (int j=0;j<4;j++) ls += expf(lsc[j]-MX);
        #pragma unroll
        for (int dd=32; dd>=1; dd>>=1) ls += __shfl_xor(ls, dd);
        if ((t&63)==0) rsum[t>>6] = ls;
        __syncthreads();
        if (t==0){
            float SUM = rsum[0]+rsum[1]+rsum[2]+rsum[3];
            if (1.0f/SUM > 0.99f){
                int pos = atomicAdd(cnt, 1);
                if (pos < ECAP) entries[pos] = make_int2(a.x, ARG);
            }
        }
    }
}

// ---------------- K3: rare-path exact correction (recomputes q,k,v) --------
__global__ __launch_bounds__(256) void correct_kernel(
    const f16* __restrict__ xq, const f16* __restrict__ wq,
    const float* __restrict__ g, const float* __restrict__ bb,
    const float* __restrict__ biases, int NU,
    const float* __restrict__ proj_w, const float* __restrict__ pg,
    const int* __restrict__ cnt, const int2* __restrict__ entries,
    float* __restrict__ out)
{
    __shared__ float xr_n[768], xr_m[768];
    __shared__ float qs[64], ks[64];
    __shared__ float hq[256];
    __shared__ float s_as;
    int total = *cnt; if (total > ECAP) total = ECAP;
    const int t = threadIdx.x;
    for (int e = blockIdx.x; e < total; e += gridDim.x){
        int2 a = entries[e];
        int bh = a.x>>10, n = a.x&1023, ms = a.y;
        int h = bh % NH, b = bh / NH;
        __syncthreads();
        for (int i=t; i<768; i+=256){
            xr_n[i] = (float)xq[((size_t)b*SEQ + n)*768 + i];
            xr_m[i] = (float)xq[((size_t)b*SEQ + ms)*768 + i];
        }
        __syncthreads();
        if (t < 128){
            int col = t & 63;
            int gcol = h*384 + (t<64 ? col : 64+col);
            const f16* wr = &wq[(size_t)gcol*768];
            const float* xr = (t<64) ? xr_n : xr_m;
            float acc = 0.f;
            for (int d=0; d<768; d++) acc = fmaf(xr[d], (float)wr[d], acc);
            float hv = __fadd_rn(__fmul_rn(acc, g[gcol]), bb[gcol]);
            float v = q8f(hv);
            if (t<64) qs[col] = v; else ks[col] = v;
        }
        __syncthreads();
        if (t < 64){
            float p = qs[t]*ks[t];
            #pragma unroll
            for (int d=32; d>=1; d>>=1) p += __shfl_xor(p, d);
            if (t == 0){
                int idx = __builtin_abs((n>>5)-(ms>>5))*32 + __builtin_abs((n&31)-(ms&31));
                float ss = __fadd_rn(__fmul_rn(p, 0.125f), biases[h*NU + idx]);
                float mx2 = fmaxf(ss, 0.f);
                float es = expf(ss-mx2), e0 = expf(-mx2);
                float Z = fmaf(1023.f, e0, es);
                s_as = q8f(es/Z);     // off-argmax weights quantize to exactly 0
            }
        }
        __syncthreads();
        {
            int gcol = h*384 + 128 + t;
            const f16* wr = &wq[(size_t)gcol*768];
            float acc = 0.f;
            for (int d=0; d<768; d++) acc = fmaf(xr_m[d], (float)wr[d], acc);
            float hv = __fadd_rn(__fmul_rn(acc, g[gcol]), bb[gcol]);
            float vq = q8f(hv);
            float o = __fmul_rn(s_as, vq);
            float c6 = fminf(fmaxf(o+3.f, 0.f), 6.f);
            hq[t] = q8f(__fdiv_rn(__fmul_rn(o, c6), 6.f));
        }
        __syncthreads();
        #pragma unroll
        for (int cc=0; cc<3; cc++){
            int c = t + cc*256;
            float s = 0.f;
            for (int d=0; d<256; d++)
                s = fmaf(hq[d], q8f(proj_w[(size_t)c*3072 + h*256 + d]), s);
            atomicAdd(&out[((size_t)b*SEQ + n)*768 + c], __fmul_rn(pg[c], s));
        }
    }
}

extern "C" void kernel_launch(void* const* d_in, const int* in_sizes, int n_in,
                              void* d_out, int out_size, void* d_ws, size_t ws_size,
                              hipStream_t stream)
{
    const float* x       = (const float*)d_in[0];
    const float* qkv_w   = (const float*)d_in[1];
    const float* qkv_g   = (const float*)d_in[2];
    const float* qkv_b   = (const float*)d_in[3];
    const float* proj_w  = (const float*)d_in[4];
    const float* proj_g  = (const float*)d_in[5];
    const float* proj_b  = (const float*)d_in[6];
    const float* biases  = (const float*)d_in[7];
    const int NU = in_sizes[7] / NH;   // 1024

    char* w = (char*)d_ws;
    f16* xq  = (f16*)w; w += (size_t)8192*768*2;
    f16* wq  = (f16*)w; w += (size_t)4608*768*2;
    f16* Qm  = (f16*)w; w += (size_t)96*1024*64*2;
    f16* Km  = (f16*)w; w += (size_t)96*1024*64*2;
    int* cnt = (int*)w;  w += 16;
    int* cnt2= (int*)w;  w += 16;
    float* Bh = (float*)w; w += 64;
    int2* entries = (int2*)w; w += (size_t)ECAP*8;
    int2* amb     = (int2*)w; w += (size_t)ECAP*8;

    prelude<<<15756, 256, 0, stream>>>(x, qkv_w, (float*)d_out, proj_b, biases, NU,
                                       xq, wq, Bh, cnt, cnt2);

    gemm_qk<<<768, 256, 0, stream>>>(xq, wq, qkv_g, qkv_b, Qm, Km);

    pass_a<<<1536, 256, 0, stream>>>(Qm, Km, Bh, cnt2, amb);

    resolve_kernel<<<256, 256, 0, stream>>>(Qm, Km, biases, NU, cnt2, amb, cnt, entries);

    correct_kernel<<<256, 256, 0, stream>>>(xq, wq, qkv_g, qkv_b, biases, NU,
                                            proj_w, proj_g, cnt, entries, (float*)d_out);
}

// Round 11
// 75.642 us; speedup vs baseline: 1.1927x; 1.1927x over previous
//
#include <hip/hip_runtime.h>

typedef _Float16 f16;
typedef _Float16 f16x8 __attribute__((ext_vector_type(8)));
typedef _Float16 f16x4 __attribute__((ext_vector_type(4)));
typedef float    f32x4 __attribute__((ext_vector_type(4)));

#define MFMA16(a,b,c) __builtin_amdgcn_mfma_f32_16x16x32_f16((a),(b),(c),0,0,0)
#define AS1(p) ((const __attribute__((address_space(1))) void*)(p))
#define AS3(p) ((__attribute__((address_space(3))) void*)(p))

constexpr int   NH   = 12;
constexpr int   SEQ  = 1024;
constexpr float INV128 = 1.0f/128.0f;
constexpr int   ECAP = 98304;
constexpr float THR_NOT = -4.5948f;   // ln(1/0.99 - 1) rounded toward safe side

__device__ __forceinline__ float q8f(float x){ return rintf(x*128.0f)*INV128; }
__device__ __forceinline__ float q4f(float x){ return rintf(x*8.0f)*0.125f; }

// ---------------- K0: merged prelude ----------------
// [0,6144)      : xq = q8(x)
// [6144,9600)   : wqk/wv = q8(qkv_w) routed: q/k rows -> wqk[1536][768], v rows -> wv[3072][768]
// [9600,15744)  : out = proj_b broadcast
// [15744,15756) : Bh[h] = max|bias_h| ; h==0 resets counters
__global__ __launch_bounds__(256) void prelude(
    const float* __restrict__ x, const float* __restrict__ qkv_w,
    float* __restrict__ out, const float* __restrict__ pb,
    const float* __restrict__ biases, int NU,
    f16* __restrict__ xq, f16* __restrict__ wqk, f16* __restrict__ wv,
    float* __restrict__ Bh, int* __restrict__ cnt, int* __restrict__ cnt2)
{
    const int b = blockIdx.x, t = threadIdx.x;
    if (b < 6144){
        int i = (b*256 + t)*4;
        float4 v = *(const float4*)(x + i);
        f16x4 o;
        o[0]=(f16)q8f(v.x); o[1]=(f16)q8f(v.y); o[2]=(f16)q8f(v.z); o[3]=(f16)q8f(v.w);
        *(f16x4*)(xq + i) = o;
    } else if (b < 9600){
        int i = ((b-6144)*256 + t)*4;        // element in qkv_w; float4 never crosses a row
        int r = i / 768, col = i - r*768;
        int head = r / 384, rr = r - head*384;
        f16* drow = (rr < 128) ? (wqk + (size_t)(head*128 + rr)*768)
                               : (wv  + (size_t)(head*256 + rr - 128)*768);
        float4 v = *(const float4*)(qkv_w + i);
        f16x4 o;
        o[0]=(f16)q8f(v.x); o[1]=(f16)q8f(v.y); o[2]=(f16)q8f(v.z); o[3]=(f16)q8f(v.w);
        *(f16x4*)(drow + col) = o;
    } else if (b < 15744){
        int i = ((b-9600)*256 + t)*4;
        int c = i % 768;
        float4 v = { pb[c], pb[c+1], pb[c+2], pb[c+3] };
        *(float4*)(out + i) = v;
    } else {
        int h = b - 15744;
        float m = 0.f;
        for (int i = t; i < NU; i += 256) m = fmaxf(m, fabsf(biases[h*NU + i]));
        #pragma unroll
        for (int d=32; d>=1; d>>=1) m = fmaxf(m, __shfl_xor(m, d));
        __shared__ float s[4];
        if ((t&63)==0) s[t>>6] = m;
        __syncthreads();
        if (t==0){
            Bh[h] = fmaxf(fmaxf(s[0],s[1]), fmaxf(s[2],s[3]));
            if (h==0){ *cnt = 0; *cnt2 = 0; }
        }
    }
}

// ---------------- K1: QK GEMM 8192x1536x768, 256x192 tile, 8 waves, BK=64 dbuf ----
__global__ __launch_bounds__(512) void gemm_qk(
    const f16* __restrict__ Aq, const f16* __restrict__ Wqk,
    const float* __restrict__ g, const float* __restrict__ bb,
    f16* __restrict__ Qm, f16* __restrict__ Km)
{
    __shared__ f16 As[2][256][64];   // 64 KB
    __shared__ f16 Bs[2][192][64];   // 48 KB
    const int t = threadIdx.x;
    const int bid = blockIdx.x;            // 0..255
    // XCD chunking: xcd = bid&7 owns 4 M-panels x all 8 N-tiles (~4.0 MB = L2)
    const int idx = bid >> 3;              // 0..31
    const int mt  = (bid & 7)*4 + (idx >> 3);
    const int nt  = idx & 7;
    const int row0 = mt*256, col0 = nt*192;
    const int w = t>>6, lane = t&63;
    const int wr = (w>>2)*128, wc = (w&3)*48;
    const int lr = lane&15, lg = lane>>4;

    // staging: per instruction a wave covers 8 rows (64 lanes x 16B = 1 KB);
    // source granule pre-swizzled by row&7 (both-sides swizzle, measured 0-conflict in R8)
    const int srow  = w*8 + (lane>>3);
    const int sgran = (lane&7) ^ (lane>>3);
    const f16* Abase = Aq  + (size_t)(row0 + srow)*768 + sgran*8;
    const f16* Bbase = Wqk + (size_t)(col0 + srow)*768 + sgran*8;

    f32x4 acc[8][3] = {};

#define STAGE(buf, kt) { \
    const int ko = (kt)*64; \
    __builtin_amdgcn_global_load_lds(AS1(Abase + (size_t)  0*768 + ko), AS3(&As[buf][w*8 +   0][0]), 16, 0, 0); \
    __builtin_amdgcn_global_load_lds(AS1(Abase + (size_t) 64*768 + ko), AS3(&As[buf][w*8 +  64][0]), 16, 0, 0); \
    __builtin_amdgcn_global_load_lds(AS1(Abase + (size_t)128*768 + ko), AS3(&As[buf][w*8 + 128][0]), 16, 0, 0); \
    __builtin_amdgcn_global_load_lds(AS1(Abase + (size_t)192*768 + ko), AS3(&As[buf][w*8 + 192][0]), 16, 0, 0); \
    __builtin_amdgcn_global_load_lds(AS1(Bbase + (size_t)  0*768 + ko), AS3(&Bs[buf][w*8 +   0][0]), 16, 0, 0); \
    __builtin_amdgcn_global_load_lds(AS1(Bbase + (size_t) 64*768 + ko), AS3(&Bs[buf][w*8 +  64][0]), 16, 0, 0); \
    __builtin_amdgcn_global_load_lds(AS1(Bbase + (size_t)128*768 + ko), AS3(&Bs[buf][w*8 + 128][0]), 16, 0, 0); }

    STAGE(0, 0)

    for (int kt = 0; kt < 12; kt++){
        __builtin_amdgcn_s_barrier();            // WAR: everyone done reading buf[kt&1^1]
        if (kt < 11){
            STAGE((kt+1)&1, kt+1)
            asm volatile("s_waitcnt vmcnt(7)" ::: "memory");   // tile kt's 7 loads complete
        } else {
            asm volatile("s_waitcnt vmcnt(0)" ::: "memory");
        }
        __builtin_amdgcn_s_barrier();            // tile kt visible to all waves

        const int bsel = kt & 1;
        #pragma unroll
        for (int kk=0; kk<2; kk++){
            const int slot = ((kk*4 + lg) ^ (lr&7))*8;
            f16x8 af[8], bf[3];
            #pragma unroll
            for (int i=0;i<8;i++)
                af[i] = *(const f16x8*)&As[bsel][wr + i*16 + lr][slot];
            #pragma unroll
            for (int j=0;j<3;j++)
                bf[j] = *(const f16x8*)&Bs[bsel][wc + j*16 + lr][slot];
            #pragma unroll
            for (int i=0;i<8;i++)
                #pragma unroll
                for (int j=0;j<3;j++)
                    acc[i][j] = MFMA16(af[i], bf[j], acc[i][j]);
        }
    }
#undef STAGE

    #pragma unroll
    for (int j=0;j<3;j++){
        int c = col0 + wc + j*16 + lr;         // 0..1535
        int head = c >> 7, rr = c & 127;
        int gcol = head*384 + rr;
        float gg = g[gcol], bv = bb[gcol];
        bool isQ = rr < 64;
        f16* dst = isQ ? Qm : Km;
        int dcol = isQ ? rr : rr - 64;
        float ksc = isQ ? 1.0f : 0.125f;
        #pragma unroll
        for (int i=0;i<8;i++){
            #pragma unroll
            for (int r=0;r<4;r++){
                int grow = row0 + wr + i*16 + lg*4 + r;
                float h = __fadd_rn(__fmul_rn(acc[i][j][r], gg), bv);
                float v4 = q4f(q8f(h));
                int bq = grow >> 10, n = grow & 1023;
                dst[((size_t)(bq*NH + head)*SEQ + n)*64 + dcol] = (f16)(v4 * ksc);
            }
        }
    }
}

// ---------------- K2: pass A — bias-free max/second-max screen ----------
__global__ __launch_bounds__(256) void pass_a(
    const f16* __restrict__ Qm, const f16* __restrict__ Km,
    const float* __restrict__ Bh,
    int* __restrict__ cnt2, int2* __restrict__ amb)
{
    __shared__ f16 Ks[128][72];

    const int t = threadIdx.x;
    const int bid = blockIdx.x;                 // 0..1535
    const int wg  = (bid & 7)*192 + (bid >> 3);
    const int bh  = wg >> 4;
    const int qt  = wg & 15;
    const int n0 = qt*64;
    const int lane = t&63, w = t>>6;
    const int lr = lane&15, lg = lane>>4;

    const float thr = THR_NOT + 2.0f*Bh[bh % NH] + 1e-4f;

    const f16* qp = &Qm[((size_t)bh*SEQ + n0 + w*16 + lr)*64];
    const f16x8 aq0 = *(const f16x8*)(qp + lg*8);
    const f16x8 aq1 = *(const f16x8*)(qp + 32 + lg*8);

    float mx[4], m2[4];
    #pragma unroll
    for (int r=0;r<4;r++){ mx[r] = -3e38f; m2[r] = -3e38f; }

    for (int kb = 0; kb < SEQ; kb += 128){
        __syncthreads();
        for (int sidx = t; sidx < 1024; sidx += 256){
            int r = sidx>>3, q = (sidx&7)*8;
            *(f16x8*)&Ks[r][q] = *(const f16x8*)&Km[((size_t)bh*SEQ + kb + r)*64 + q];
        }
        __syncthreads();
        #pragma unroll
        for (int ct=0; ct<8; ct++){
            f16x8 b0 = *(const f16x8*)&Ks[ct*16+lr][lg*8];
            f16x8 b1 = *(const f16x8*)&Ks[ct*16+lr][32+lg*8];
            f32x4 c = {};
            c = MFMA16(aq0, b0, c);
            c = MFMA16(aq1, b1, c);
            #pragma unroll
            for (int r=0;r<4;r++){
                float sc = c[r];
                float om = mx[r];
                m2[r] = fmaxf(m2[r], fminf(sc, om));
                mx[r] = fmaxf(om, sc);
            }
        }
    }

    #pragma unroll
    for (int r=0;r<4;r++){
        float mxv = mx[r], m2v = m2[r];
        #pragma unroll
        for (int d=1; d<16; d<<=1){
            float mo  = __shfl_xor(mxv, d);
            float m2o = __shfl_xor(m2v, d);
            float sec = fmaxf(fminf(mxv, mo), (mxv >= mo) ? m2v : m2o);
            mxv = fmaxf(mxv, mo);
            m2v = sec;
        }
        if (lr == 0){
            if (m2v - mxv < thr){
                int n = n0 + w*16 + lg*4 + r;
                int pos = atomicAdd(cnt2, 1);
                if (pos < ECAP) amb[pos] = make_int2((bh<<10) | n, 0);
            }
        }
    }
}

// ---------------- K2b: exact biased resolve (flag + argmax) ----------
__global__ __launch_bounds__(256) void resolve_kernel(
    const f16* __restrict__ Qm, const f16* __restrict__ Km,
    const float* __restrict__ biases, int NU,
    const int* __restrict__ cnt2, const int2* __restrict__ amb,
    int* __restrict__ cnt, int2* __restrict__ entries)
{
    __shared__ float qrow[64];
    __shared__ float rmax[4], rsum[4];
    __shared__ int   rarg[4];
    int total = *cnt2; if (total > ECAP) total = ECAP;
    const int t = threadIdx.x;
    for (int e = blockIdx.x; e < total; e += gridDim.x){
        int2 a = amb[e];
        int bh = a.x>>10, n = a.x&1023, h = bh % NH;
        __syncthreads();
        if (t < 64) qrow[t] = (float)Qm[((size_t)bh*SEQ + n)*64 + t];
        __syncthreads();
        int rn = n>>5, cnn = n&31;
        float lmax = -3e38f; int larg = 0; float lsc[4];
        #pragma unroll
        for (int j=0;j<4;j++){
            int m = t + j*256;
            const f16* kp = &Km[((size_t)bh*SEQ + m)*64];
            float d = 0.f;
            for (int u=0; u<64; u+=8){
                f16x8 kv = *(const f16x8*)(kp+u);
                #pragma unroll
                for (int z=0; z<8; z++) d += qrow[u+z]*(float)kv[z];
            }
            int idx = __builtin_abs(rn-(m>>5))*32 + __builtin_abs(cnn-(m&31));
            lsc[j] = d + biases[h*NU + idx];
            if (lsc[j] > lmax){ lmax = lsc[j]; larg = m; }
        }
        #pragma unroll
        for (int dd=32; dd>=1; dd>>=1){
            float mo = __shfl_xor(lmax, dd);
            int   ao = __shfl_xor(larg, dd);
            if (mo > lmax){ lmax = mo; larg = ao; }
        }
        if ((t&63)==0){ rmax[t>>6] = lmax; rarg[t>>6] = larg; }
        __syncthreads();
        float MX = rmax[0]; int ARG = rarg[0];
        #pragma unroll
        for (int k=1;k<4;k++){ if (rmax[k] > MX){ MX = rmax[k]; ARG = rarg[k]; } }
        float ls = 0.f;
        #pragma unroll
        for (int j=0;j<4;j++) ls += expf(lsc[j]-MX);
        #pragma unroll
        for (int dd=32; dd>=1; dd>>=1) ls += __shfl_xor(ls, dd);
        if ((t&63)==0) rsum[t>>6] = ls;
        __syncthreads();
        if (t==0){
            float SUM = rsum[0]+rsum[1]+rsum[2]+rsum[3];
            if (1.0f/SUM > 0.99f){
                int pos = atomicAdd(cnt, 1);
                if (pos < ECAP) entries[pos] = make_int2(a.x, ARG);
            }
        }
    }
}

// ---------------- K3: rare-path exact correction (recomputes q,k,v) --------
__global__ __launch_bounds__(256) void correct_kernel(
    const f16* __restrict__ xq, const f16* __restrict__ wqk, const f16* __restrict__ wv,
    const float* __restrict__ g, const float* __restrict__ bb,
    const float* __restrict__ biases, int NU,
    const float* __restrict__ proj_w, const float* __restrict__ pg,
    const int* __restrict__ cnt, const int2* __restrict__ entries,
    float* __restrict__ out)
{
    __shared__ float xr_n[768], xr_m[768];
    __shared__ float qs[64], ks[64];
    __shared__ float hq[256];
    __shared__ float s_as;
    int total = *cnt; if (total > ECAP) total = ECAP;
    const int t = threadIdx.x;
    for (int e = blockIdx.x; e < total; e += gridDim.x){
        int2 a = entries[e];
        int bh = a.x>>10, n = a.x&1023, ms = a.y;
        int h = bh % NH, b = bh / NH;
        __syncthreads();
        for (int i=t; i<768; i+=256){
            xr_n[i] = (float)xq[((size_t)b*SEQ + n)*768 + i];
            xr_m[i] = (float)xq[((size_t)b*SEQ + ms)*768 + i];
        }
        __syncthreads();
        if (t < 128){
            int col = t & 63;
            int qkr  = h*128 + (t<64 ? col : 64+col);
            int gcol = h*384 + (t<64 ? col : 64+col);
            const f16* wr = &wqk[(size_t)qkr*768];
            const float* xr = (t<64) ? xr_n : xr_m;
            float acc = 0.f;
            for (int d=0; d<768; d++) acc = fmaf(xr[d], (float)wr[d], acc);
            float hv = __fadd_rn(__fmul_rn(acc, g[gcol]), bb[gcol]);
            float v = q8f(hv);
            if (t<64) qs[col] = v; else ks[col] = v;
        }
        __syncthreads();
        if (t < 64){
            float p = qs[t]*ks[t];
            #pragma unroll
            for (int d=32; d>=1; d>>=1) p += __shfl_xor(p, d);
            if (t == 0){
                int idx = __builtin_abs((n>>5)-(ms>>5))*32 + __builtin_abs((n&31)-(ms&31));
                float ss = __fadd_rn(__fmul_rn(p, 0.125f), biases[h*NU + idx]);
                float mx2 = fmaxf(ss, 0.f);
                float es = expf(ss-mx2), e0 = expf(-mx2);
                float Z = fmaf(1023.f, e0, es);
                s_as = q8f(es/Z);     // off-argmax weights quantize to exactly 0
            }
        }
        __syncthreads();
        {
            int gcol = h*384 + 128 + t;
            const f16* wr = &wv[(size_t)(h*256 + t)*768];
            float acc = 0.f;
            for (int d=0; d<768; d++) acc = fmaf(xr_m[d], (float)wr[d], acc);
            float hv = __fadd_rn(__fmul_rn(acc, g[gcol]), bb[gcol]);
            float vq = q8f(hv);
            float o = __fmul_rn(s_as, vq);
            float c6 = fminf(fmaxf(o+3.f, 0.f), 6.f);
            hq[t] = q8f(__fdiv_rn(__fmul_rn(o, c6), 6.f));
        }
        __syncthreads();
        #pragma unroll
        for (int cc=0; cc<3; cc++){
            int c = t + cc*256;
            float s = 0.f;
            for (int d=0; d<256; d++)
                s = fmaf(hq[d], q8f(proj_w[(size_t)c*3072 + h*256 + d]), s);
            atomicAdd(&out[((size_t)b*SEQ + n)*768 + c], __fmul_rn(pg[c], s));
        }
    }
}

extern "C" void kernel_launch(void* const* d_in, const int* in_sizes, int n_in,
                              void* d_out, int out_size, void* d_ws, size_t ws_size,
                              hipStream_t stream)
{
    const float* x       = (const float*)d_in[0];
    const float* qkv_w   = (const float*)d_in[1];
    const float* qkv_g   = (const float*)d_in[2];
    const float* qkv_b   = (const float*)d_in[3];
    const float* proj_w  = (const float*)d_in[4];
    const float* proj_g  = (const float*)d_in[5];
    const float* proj_b  = (const float*)d_in[6];
    const float* biases  = (const float*)d_in[7];
    const int NU = in_sizes[7] / NH;   // 1024

    char* w = (char*)d_ws;
    f16* xq  = (f16*)w; w += (size_t)8192*768*2;
    f16* wqk = (f16*)w; w += (size_t)1536*768*2;
    f16* wv  = (f16*)w; w += (size_t)3072*768*2;
    f16* Qm  = (f16*)w; w += (size_t)96*1024*64*2;
    f16* Km  = (f16*)w; w += (size_t)96*1024*64*2;
    int* cnt = (int*)w;  w += 16;
    int* cnt2= (int*)w;  w += 16;
    float* Bh = (float*)w; w += 64;
    int2* entries = (int2*)w; w += (size_t)ECAP*8;
    int2* amb     = (int2*)w; w += (size_t)ECAP*8;

    prelude<<<15756, 256, 0, stream>>>(x, qkv_w, (float*)d_out, proj_b, biases, NU,
                                       xq, wqk, wv, Bh, cnt, cnt2);

    gemm_qk<<<256, 512, 0, stream>>>(xq, wqk, qkv_g, qkv_b, Qm, Km);

    pass_a<<<1536, 256, 0, stream>>>(Qm, Km, Bh, cnt2, amb);

    resolve_kernel<<<256, 256, 0, stream>>>(Qm, Km, biases, NU, cnt2, amb, cnt, entries);

    correct_kernel<<<256, 256, 0, stream>>>(xq, wqk, wv, qkv_g, qkv_b, biases, NU,
                                            proj_w, proj_g, cnt, entries, (float*)d_out);
}

// Round 12
// 62.963 us; speedup vs baseline: 1.4329x; 1.2014x over previous
//
#include <hip/hip_runtime.h>

typedef _Float16 f16;
typedef _Float16 f16x8 __attribute__((ext_vector_type(8)));
typedef _Float16 f16x4 __attribute__((ext_vector_type(4)));
typedef float    f32x4 __attribute__((ext_vector_type(4)));
typedef int      i32x4 __attribute__((ext_vector_type(4)));

#define MFMA16(a,b,c) __builtin_amdgcn_mfma_f32_16x16x32_f16((a),(b),(c),0,0,0)
#define MFMAI8(a,b,c) __builtin_amdgcn_mfma_i32_16x16x64_i8((a),(b),(c),0,0,0)
#define AS1(p) ((const __attribute__((address_space(1))) void*)(p))
#define AS3(p) ((__attribute__((address_space(3))) void*)(p))

constexpr int   NH   = 12;
constexpr int   SEQ  = 1024;
constexpr float INV128 = 1.0f/128.0f;
constexpr int   ECAP = 98304;
constexpr float THR_NOT = -4.5948f;   // ln(1/0.99 - 1) rounded toward safe side

__device__ __forceinline__ float q8f(float x){ return rintf(x*128.0f)*INV128; }
__device__ __forceinline__ float q4f(float x){ return rintf(x*8.0f)*0.125f; }

// ---------------- K0: merged prelude ----------------
__global__ __launch_bounds__(256) void prelude(
    const float* __restrict__ x, const float* __restrict__ qkv_w,
    float* __restrict__ out, const float* __restrict__ pb,
    const float* __restrict__ biases, int NU,
    f16* __restrict__ xq, f16* __restrict__ wqk, f16* __restrict__ wv,
    float* __restrict__ Bh, int* __restrict__ cnt2)
{
    const int b = blockIdx.x, t = threadIdx.x;
    if (b < 6144){
        int i = (b*256 + t)*4;
        float4 v = *(const float4*)(x + i);
        f16x4 o;
        o[0]=(f16)q8f(v.x); o[1]=(f16)q8f(v.y); o[2]=(f16)q8f(v.z); o[3]=(f16)q8f(v.w);
        *(f16x4*)(xq + i) = o;
    } else if (b < 9600){
        int i = ((b-6144)*256 + t)*4;        // float4 never crosses a 768-row
        int r = i / 768, col = i - r*768;
        int head = r / 384, rr = r - head*384;
        f16* drow = (rr < 128) ? (wqk + (size_t)(head*128 + rr)*768)
                               : (wv  + (size_t)(head*256 + rr - 128)*768);
        float4 v = *(const float4*)(qkv_w + i);
        f16x4 o;
        o[0]=(f16)q8f(v.x); o[1]=(f16)q8f(v.y); o[2]=(f16)q8f(v.z); o[3]=(f16)q8f(v.w);
        *(f16x4*)(drow + col) = o;
    } else if (b < 15744){
        int i = ((b-9600)*256 + t)*4;
        int c = i % 768;
        float4 v = { pb[c], pb[c+1], pb[c+2], pb[c+3] };
        *(float4*)(out + i) = v;
    } else {
        int h = b - 15744;
        float m = 0.f;
        for (int i = t; i < NU; i += 256) m = fmaxf(m, fabsf(biases[h*NU + i]));
        #pragma unroll
        for (int d=32; d>=1; d>>=1) m = fmaxf(m, __shfl_xor(m, d));
        __shared__ float s[4];
        if ((t&63)==0) s[t>>6] = m;
        __syncthreads();
        if (t==0){
            Bh[h] = fmaxf(fmaxf(s[0],s[1]), fmaxf(s[2],s[3]));
            if (h==0) *cnt2 = 0;
        }
    }
}

// ---------------- K1: QK GEMM 8192x1536x768, 256x192 tile, int8 output ----
__global__ __launch_bounds__(512) void gemm_qk(
    const f16* __restrict__ Aq, const f16* __restrict__ Wqk,
    const float* __restrict__ g, const float* __restrict__ bb,
    signed char* __restrict__ Qi, signed char* __restrict__ Ki)
{
    __shared__ f16 As[2][256][64];   // 64 KB
    __shared__ f16 Bs[2][192][64];   // 48 KB
    const int t = threadIdx.x;
    const int bid = blockIdx.x;            // 0..255
    const int idx = bid >> 3;
    const int mt  = (bid & 7)*4 + (idx >> 3);
    const int nt  = idx & 7;
    const int row0 = mt*256, col0 = nt*192;
    const int w = t>>6, lane = t&63;
    const int wr = (w>>2)*128, wc = (w&3)*48;
    const int lr = lane&15, lg = lane>>4;

    const int srow  = w*8 + (lane>>3);
    const int sgran = (lane&7) ^ (lane>>3);
    const f16* Abase = Aq  + (size_t)(row0 + srow)*768 + sgran*8;
    const f16* Bbase = Wqk + (size_t)(col0 + srow)*768 + sgran*8;

    f32x4 acc[8][3] = {};

#define STAGE(buf, kt) { \
    const int ko = (kt)*64; \
    __builtin_amdgcn_global_load_lds(AS1(Abase + (size_t)  0*768 + ko), AS3(&As[buf][w*8 +   0][0]), 16, 0, 0); \
    __builtin_amdgcn_global_load_lds(AS1(Abase + (size_t) 64*768 + ko), AS3(&As[buf][w*8 +  64][0]), 16, 0, 0); \
    __builtin_amdgcn_global_load_lds(AS1(Abase + (size_t)128*768 + ko), AS3(&As[buf][w*8 + 128][0]), 16, 0, 0); \
    __builtin_amdgcn_global_load_lds(AS1(Abase + (size_t)192*768 + ko), AS3(&As[buf][w*8 + 192][0]), 16, 0, 0); \
    __builtin_amdgcn_global_load_lds(AS1(Bbase + (size_t)  0*768 + ko), AS3(&Bs[buf][w*8 +   0][0]), 16, 0, 0); \
    __builtin_amdgcn_global_load_lds(AS1(Bbase + (size_t) 64*768 + ko), AS3(&Bs[buf][w*8 +  64][0]), 16, 0, 0); \
    __builtin_amdgcn_global_load_lds(AS1(Bbase + (size_t)128*768 + ko), AS3(&Bs[buf][w*8 + 128][0]), 16, 0, 0); }

    STAGE(0, 0)

    for (int kt = 0; kt < 12; kt++){
        __builtin_amdgcn_s_barrier();
        if (kt < 11){
            STAGE((kt+1)&1, kt+1)
            asm volatile("s_waitcnt vmcnt(7)" ::: "memory");
        } else {
            asm volatile("s_waitcnt vmcnt(0)" ::: "memory");
        }
        __builtin_amdgcn_s_barrier();

        const int bsel = kt & 1;
        #pragma unroll
        for (int kk=0; kk<2; kk++){
            const int slot = ((kk*4 + lg) ^ (lr&7))*8;
            f16x8 af[8], bf[3];
            #pragma unroll
            for (int i=0;i<8;i++)
                af[i] = *(const f16x8*)&As[bsel][wr + i*16 + lr][slot];
            #pragma unroll
            for (int j=0;j<3;j++)
                bf[j] = *(const f16x8*)&Bs[bsel][wc + j*16 + lr][slot];
            #pragma unroll
            for (int i=0;i<8;i++)
                #pragma unroll
                for (int j=0;j<3;j++)
                    acc[i][j] = MFMA16(af[i], bf[j], acc[i][j]);
        }
    }
#undef STAGE

    #pragma unroll
    for (int j=0;j<3;j++){
        int c = col0 + wc + j*16 + lr;         // 0..1535
        int head = c >> 7, rr = c & 127;
        int gcol = head*384 + rr;
        float gg = g[gcol], bv = bb[gcol];
        signed char* dst = (rr < 64) ? Qi : Ki;
        int dcol = rr & 63;
        #pragma unroll
        for (int i=0;i<8;i++){
            #pragma unroll
            for (int r=0;r<4;r++){
                int grow = row0 + wr + i*16 + lg*4 + r;
                float h = __fadd_rn(__fmul_rn(acc[i][j][r], gg), bv);
                int iv = (int)rintf(q8f(h)*8.0f);     // q4 value x8: exact int8
                int bq = grow >> 10, n = grow & 1023;
                dst[((size_t)(bq*NH + head)*SEQ + n)*64 + dcol] = (signed char)iv;
            }
        }
    }
}

// ---------------- K2: pass A — int8 MFMA bias-free max/second-max screen ----
__global__ __launch_bounds__(256) void pass_a(
    const signed char* __restrict__ Qi, const signed char* __restrict__ Ki,
    const float* __restrict__ Bh,
    int* __restrict__ cnt2, int2* __restrict__ amb)
{
    __shared__ signed char Ks[128][64];

    const int t = threadIdx.x;
    const int bid = blockIdx.x;                 // 0..1535
    const int wg  = (bid & 7)*192 + (bid >> 3);
    const int bh  = wg >> 4;
    const int qt  = wg & 15;
    const int n0 = qt*64;
    const int lane = t&63, w = t>>6;
    const int lr = lane&15, lg = lane>>4;

    const float thr512 = (THR_NOT + 2.0f*Bh[bh % NH] + 1e-4f) * 512.0f;

    // lane's Q fragment: row n0+w*16+lr, bytes [lg*16, lg*16+16)
    const signed char* qp = Qi + ((size_t)bh*SEQ + n0 + w*16 + lr)*64;
    const i32x4 aq = *(const i32x4*)(qp + lg*16);

    const signed char* Kb = Ki + (size_t)bh*SEQ*64;

    int mx[4], m2[4];
    #pragma unroll
    for (int r=0;r<4;r++){ mx[r] = -(1<<30); m2[r] = -(1<<30); }

    for (int kb = 0; kb < SEQ; kb += 128){
        __syncthreads();
        for (int s = t; s < 512; s += 256){
            int r = s>>2, gsw = s&3;
            int src = (gsw ^ (r&3))*16;           // both-sides swizzle (rule 21)
            *(i32x4*)&Ks[r][gsw*16] = *(const i32x4*)(Kb + (size_t)(kb + r)*64 + src);
        }
        __syncthreads();
        #pragma unroll
        for (int ct=0; ct<8; ct++){
            const int row = ct*16 + lr;
            i32x4 bq = *(const i32x4*)&Ks[row][(lg ^ (lr&3))*16];
            i32x4 c = {0,0,0,0};
            c = MFMAI8(aq, bq, c);
            #pragma unroll
            for (int r=0;r<4;r++){
                int sc = c[r];
                int om = mx[r];
                m2[r] = max(m2[r], min(sc, om));
                mx[r] = max(om, sc);
            }
        }
    }

    #pragma unroll
    for (int r=0;r<4;r++){
        int mxv = mx[r], m2v = m2[r];
        #pragma unroll
        for (int d=1; d<16; d<<=1){
            int mo  = __shfl_xor(mxv, d);
            int m2o = __shfl_xor(m2v, d);
            int sec = max(min(mxv, mo), (mxv >= mo) ? m2v : m2o);
            mxv = max(mxv, mo);
            m2v = sec;
        }
        if (lr == 0){
            if ((float)(m2v - mxv) < thr512){
                int n = n0 + w*16 + lg*4 + r;
                int pos = atomicAdd(cnt2, 1);
                if (pos < ECAP) amb[pos] = make_int2((bh<<10) | n, 0);
            }
        }
    }
}

// ---------------- K3: merged tail — exact resolve + rare-path correction ----
__global__ __launch_bounds__(256) void tail_kernel(
    const signed char* __restrict__ Qi, const signed char* __restrict__ Ki,
    const float* __restrict__ biases, int NU,
    const f16* __restrict__ xq, const f16* __restrict__ wqk, const f16* __restrict__ wv,
    const float* __restrict__ g, const float* __restrict__ bb,
    const float* __restrict__ proj_w, const float* __restrict__ pg,
    const int* __restrict__ cnt2, const int2* __restrict__ amb,
    float* __restrict__ out)
{
    __shared__ int   qr[64];
    __shared__ float rmax[4], rsum[4];
    __shared__ int   rarg[4];
    __shared__ float xr_n[768], xr_m[768];
    __shared__ float qs[64], ks[64];
    __shared__ float hq[256];
    __shared__ float s_as;
    __shared__ int   s_ms, s_flag;
    int total = *cnt2; if (total > ECAP) total = ECAP;
    const int t = threadIdx.x;
    for (int e = blockIdx.x; e < total; e += gridDim.x){
        int2 a = amb[e];
        int bh = a.x>>10, n = a.x&1023;
        int h = bh % NH, b = bh / NH;
        __syncthreads();
        if (t < 64) qr[t] = (int)Qi[((size_t)bh*SEQ + n)*64 + t];
        __syncthreads();

        // ---- exact biased resolve (int dot, bit-identical to reference) ----
        int rn = n>>5, cnn = n&31;
        float lmax = -3e38f; int larg = 0; float lsc[4];
        #pragma unroll
        for (int j=0;j<4;j++){
            int m = t + j*256;
            const signed char* kp = &Ki[((size_t)bh*SEQ + m)*64];
            int d = 0;
            for (int u=0; u<64; u++) d += qr[u]*(int)kp[u];
            int idx = __builtin_abs(rn-(m>>5))*32 + __builtin_abs(cnn-(m&31));
            lsc[j] = (float)d*(1.0f/512.0f) + biases[h*NU + idx];
            if (lsc[j] > lmax){ lmax = lsc[j]; larg = m; }
        }
        #pragma unroll
        for (int dd=32; dd>=1; dd>>=1){
            float mo = __shfl_xor(lmax, dd);
            int   ao = __shfl_xor(larg, dd);
            if (mo > lmax){ lmax = mo; larg = ao; }
        }
        if ((t&63)==0){ rmax[t>>6] = lmax; rarg[t>>6] = larg; }
        __syncthreads();
        float MX = rmax[0]; int ARG = rarg[0];
        #pragma unroll
        for (int k=1;k<4;k++){ if (rmax[k] > MX){ MX = rmax[k]; ARG = rarg[k]; } }
        float ls = 0.f;
        #pragma unroll
        for (int j=0;j<4;j++) ls += expf(lsc[j]-MX);
        #pragma unroll
        for (int dd=32; dd>=1; dd>>=1) ls += __shfl_xor(ls, dd);
        if ((t&63)==0) rsum[t>>6] = ls;
        __syncthreads();
        if (t==0){
            float SUM = rsum[0]+rsum[1]+rsum[2]+rsum[3];
            s_flag = (1.0f/SUM > 0.99f);
            s_ms = ARG;
        }
        __syncthreads();
        if (!s_flag) continue;
        const int ms = s_ms;

        // ---- correction: recompute q,k,v at q8 precision from xq . wqk/wv ----
        for (int i=t; i<768; i+=256){
            xr_n[i] = (float)xq[((size_t)b*SEQ + n)*768 + i];
            xr_m[i] = (float)xq[((size_t)b*SEQ + ms)*768 + i];
        }
        __syncthreads();
        if (t < 128){
            int col = t & 63;
            int qkr  = h*128 + (t<64 ? col : 64+col);
            int gcol = h*384 + (t<64 ? col : 64+col);
            const f16* wr = &wqk[(size_t)qkr*768];
            const float* xr = (t<64) ? xr_n : xr_m;
            float acc = 0.f;
            for (int d=0; d<768; d++) acc = fmaf(xr[d], (float)wr[d], acc);
            float hv = __fadd_rn(__fmul_rn(acc, g[gcol]), bb[gcol]);
            float v = q8f(hv);
            if (t<64) qs[col] = v; else ks[col] = v;
        }
        __syncthreads();
        if (t < 64){
            float p = qs[t]*ks[t];
            #pragma unroll
            for (int d=32; d>=1; d>>=1) p += __shfl_xor(p, d);
            if (t == 0){
                int idx = __builtin_abs((n>>5)-(ms>>5))*32 + __builtin_abs((n&31)-(ms&31));
                float ss = __fadd_rn(__fmul_rn(p, 0.125f), biases[h*NU + idx]);
                float mx2 = fmaxf(ss, 0.f);
                float es = expf(ss-mx2), e0 = expf(-mx2);
                float Z = fmaf(1023.f, e0, es);
                s_as = q8f(es/Z);     // off-argmax weights quantize to exactly 0
            }
        }
        __syncthreads();
        {
            int gcol = h*384 + 128 + t;
            const f16* wr = &wv[(size_t)(h*256 + t)*768];
            float acc = 0.f;
            for (int d=0; d<768; d++) acc = fmaf(xr_m[d], (float)wr[d], acc);
            float hv = __fadd_rn(__fmul_rn(acc, g[gcol]), bb[gcol]);
            float vq = q8f(hv);
            float o = __fmul_rn(s_as, vq);
            float c6 = fminf(fmaxf(o+3.f, 0.f), 6.f);
            hq[t] = q8f(__fdiv_rn(__fmul_rn(o, c6), 6.f));
        }
        __syncthreads();
        #pragma unroll
        for (int cc=0; cc<3; cc++){
            int c = t + cc*256;
            float s = 0.f;
            for (int d=0; d<256; d++)
                s = fmaf(hq[d], q8f(proj_w[(size_t)c*3072 + h*256 + d]), s);
            atomicAdd(&out[((size_t)b*SEQ + n)*768 + c], __fmul_rn(pg[c], s));
        }
    }
}

extern "C" void kernel_launch(void* const* d_in, const int* in_sizes, int n_in,
                              void* d_out, int out_size, void* d_ws, size_t ws_size,
                              hipStream_t stream)
{
    const float* x       = (const float*)d_in[0];
    const float* qkv_w   = (const float*)d_in[1];
    const float* qkv_g   = (const float*)d_in[2];
    const float* qkv_b   = (const float*)d_in[3];
    const float* proj_w  = (const float*)d_in[4];
    const float* proj_g  = (const float*)d_in[5];
    const float* proj_b  = (const float*)d_in[6];
    const float* biases  = (const float*)d_in[7];
    const int NU = in_sizes[7] / NH;   // 1024

    char* w = (char*)d_ws;
    f16* xq  = (f16*)w; w += (size_t)8192*768*2;
    f16* wqk = (f16*)w; w += (size_t)1536*768*2;
    f16* wv  = (f16*)w; w += (size_t)3072*768*2;
    signed char* Qi = (signed char*)w; w += (size_t)96*1024*64;
    signed char* Ki = (signed char*)w; w += (size_t)96*1024*64;
    int* cnt2= (int*)w;  w += 16;
    float* Bh = (float*)w; w += 64;
    int2* amb = (int2*)w; w += (size_t)ECAP*8;

    prelude<<<15756, 256, 0, stream>>>(x, qkv_w, (float*)d_out, proj_b, biases, NU,
                                       xq, wqk, wv, Bh, cnt2);

    gemm_qk<<<256, 512, 0, stream>>>(xq, wqk, qkv_g, qkv_b, Qi, Ki);

    pass_a<<<1536, 256, 0, stream>>>(Qi, Ki, Bh, cnt2, amb);

    tail_kernel<<<256, 256, 0, stream>>>(Qi, Ki, biases, NU, xq, wqk, wv,
                                         qkv_g, qkv_b, proj_w, proj_g,
                                         cnt2, amb, (float*)d_out);
}

// Round 13
// 57.270 us; speedup vs baseline: 1.5754x; 1.0994x over previous
//
#include <hip/hip_runtime.h>

typedef _Float16 f16;
typedef _Float16 f16x8 __attribute__((ext_vector_type(8)));
typedef _Float16 f16x4 __attribute__((ext_vector_type(4)));
typedef float    f32x4 __attribute__((ext_vector_type(4)));
typedef int      i32x4 __attribute__((ext_vector_type(4)));

#define MFMA16(a,b,c) __builtin_amdgcn_mfma_f32_16x16x32_f16((a),(b),(c),0,0,0)
#define MFMAI8(a,b,c) __builtin_amdgcn_mfma_i32_16x16x64_i8((a),(b),(c),0,0,0)
#define AS1(p) ((const __attribute__((address_space(1))) void*)(p))
#define AS3(p) ((__attribute__((address_space(3))) void*)(p))

constexpr int   NH   = 12;
constexpr int   SEQ  = 1024;
constexpr float INV128 = 1.0f/128.0f;
constexpr int   ECAP = 98304;
constexpr float THR_NOT = -4.5948f;   // ln(1/0.99 - 1) rounded toward safe side

__device__ __forceinline__ float q8f(float x){ return rintf(x*128.0f)*INV128; }
__device__ __forceinline__ float q4f(float x){ return rintf(x*8.0f)*0.125f; }

// ---------------- K0: merged prelude ----------------
// [0,6144)       : xq = q8(x)
// [6144,7296)    : wqk = q8(qkv_w q/k rows only)   (wqk row r <- src row (r>>7)*384 + (r&127))
// [7296,13440)   : out = proj_b broadcast
// [13440,13452)  : Bh[h] = max|bias_h| ; h==0 resets counter
__global__ __launch_bounds__(256) void prelude(
    const float* __restrict__ x, const float* __restrict__ qkv_w,
    float* __restrict__ out, const float* __restrict__ pb,
    const float* __restrict__ biases, int NU,
    f16* __restrict__ xq, f16* __restrict__ wqk,
    float* __restrict__ Bh, int* __restrict__ cnt2)
{
    const int b = blockIdx.x, t = threadIdx.x;
    if (b < 6144){
        int i = (b*256 + t)*4;
        float4 v = *(const float4*)(x + i);
        f16x4 o;
        o[0]=(f16)q8f(v.x); o[1]=(f16)q8f(v.y); o[2]=(f16)q8f(v.z); o[3]=(f16)q8f(v.w);
        *(f16x4*)(xq + i) = o;
    } else if (b < 7296){
        int i = ((b-6144)*256 + t)*4;        // element in wqk [1536][768]
        int r = i / 768, col = i - r*768;
        int srow = (r>>7)*384 + (r&127);
        float4 v = *(const float4*)(qkv_w + (size_t)srow*768 + col);
        f16x4 o;
        o[0]=(f16)q8f(v.x); o[1]=(f16)q8f(v.y); o[2]=(f16)q8f(v.z); o[3]=(f16)q8f(v.w);
        *(f16x4*)(wqk + i) = o;
    } else if (b < 13440){
        int i = ((b-7296)*256 + t)*4;
        int c = i % 768;
        float4 v = { pb[c], pb[c+1], pb[c+2], pb[c+3] };
        *(float4*)(out + i) = v;
    } else {
        int h = b - 13440;
        float m = 0.f;
        for (int i = t; i < NU; i += 256) m = fmaxf(m, fabsf(biases[h*NU + i]));
        #pragma unroll
        for (int d=32; d>=1; d>>=1) m = fmaxf(m, __shfl_xor(m, d));
        __shared__ float s[4];
        if ((t&63)==0) s[t>>6] = m;
        __syncthreads();
        if (t==0){
            Bh[h] = fmaxf(fmaxf(s[0],s[1]), fmaxf(s[2],s[3]));
            if (h==0) *cnt2 = 0;
        }
    }
}

// ---------------- K1: QK GEMM 8192x1536x768 — 128x192 tile, 4 waves, 2 blocks/CU ----
__global__ __launch_bounds__(256, 2) void gemm_qk(
    const f16* __restrict__ Aq, const f16* __restrict__ Wqk,
    const float* __restrict__ g, const float* __restrict__ bb,
    signed char* __restrict__ Qi, signed char* __restrict__ Ki)
{
    __shared__ f16 As[2][128][64];   // 32 KB
    __shared__ f16 Bs[2][192][64];   // 48 KB   (80 KB total -> 2 blocks/CU)
    const int t = threadIdx.x;
    const int bid = blockIdx.x;              // 0..511
    const int xcd = bid & 7, idx = bid >> 3; // per-XCD: 8 M-panels x 8 N-tiles (~4 MB = L2)
    const int mt  = xcd*8 + (idx >> 3);      // 0..63
    const int nt  = idx & 7;                 // 0..7
    const int row0 = mt*128, col0 = nt*192;
    const int w = t>>6, lane = t&63;
    const int wr = (w>>1)*64, wc = (w&1)*96;
    const int lr = lane&15, lg = lane>>4;

    // staging: 1 instr = 8 rows x 128 B; dest LDS linear, source granule pre-swizzled
    const int rloc  = lane>>3;                 // 0..7
    const int sgran = (lane&7) ^ rloc;
    const f16* Abase = Aq  + (size_t)(row0 + w*32 + rloc)*768 + sgran*8;
    const f16* Bbase = Wqk + (size_t)(col0 + w*48 + rloc)*768 + sgran*8;

    f32x4 acc[4][6] = {};

#define STAGE(buf, kt) { \
    const int ko = (kt)*64; \
    __builtin_amdgcn_global_load_lds(AS1(Abase + (size_t) 0*768 + ko), AS3(&As[buf][w*32 +  0][0]), 16, 0, 0); \
    __builtin_amdgcn_global_load_lds(AS1(Abase + (size_t) 8*768 + ko), AS3(&As[buf][w*32 +  8][0]), 16, 0, 0); \
    __builtin_amdgcn_global_load_lds(AS1(Abase + (size_t)16*768 + ko), AS3(&As[buf][w*32 + 16][0]), 16, 0, 0); \
    __builtin_amdgcn_global_load_lds(AS1(Abase + (size_t)24*768 + ko), AS3(&As[buf][w*32 + 24][0]), 16, 0, 0); \
    __builtin_amdgcn_global_load_lds(AS1(Bbase + (size_t) 0*768 + ko), AS3(&Bs[buf][w*48 +  0][0]), 16, 0, 0); \
    __builtin_amdgcn_global_load_lds(AS1(Bbase + (size_t) 8*768 + ko), AS3(&Bs[buf][w*48 +  8][0]), 16, 0, 0); \
    __builtin_amdgcn_global_load_lds(AS1(Bbase + (size_t)16*768 + ko), AS3(&Bs[buf][w*48 + 16][0]), 16, 0, 0); \
    __builtin_amdgcn_global_load_lds(AS1(Bbase + (size_t)24*768 + ko), AS3(&Bs[buf][w*48 + 24][0]), 16, 0, 0); \
    __builtin_amdgcn_global_load_lds(AS1(Bbase + (size_t)32*768 + ko), AS3(&Bs[buf][w*48 + 32][0]), 16, 0, 0); \
    __builtin_amdgcn_global_load_lds(AS1(Bbase + (size_t)40*768 + ko), AS3(&Bs[buf][w*48 + 40][0]), 16, 0, 0); }

    STAGE(0, 0)

    for (int kt = 0; kt < 12; kt++){
        __builtin_amdgcn_s_barrier();             // WAR: all waves done reading buf[kt&1]
        if (kt < 11){
            STAGE((kt+1)&1, kt+1)
            asm volatile("s_waitcnt vmcnt(10)" ::: "memory");   // tile kt's 10 loads done
        } else {
            asm volatile("s_waitcnt vmcnt(0)" ::: "memory");
        }
        __builtin_amdgcn_s_barrier();             // tile kt visible to all waves

        const int bsel = kt & 1;
        #pragma unroll
        for (int kk=0; kk<2; kk++){
            const int slot = ((kk*4 + lg) ^ (lr&7))*8;
            f16x8 af[4], bf[6];
            #pragma unroll
            for (int i=0;i<4;i++)
                af[i] = *(const f16x8*)&As[bsel][wr + i*16 + lr][slot];
            #pragma unroll
            for (int j=0;j<6;j++)
                bf[j] = *(const f16x8*)&Bs[bsel][wc + j*16 + lr][slot];
            __builtin_amdgcn_s_setprio(1);
            #pragma unroll
            for (int i=0;i<4;i++)
                #pragma unroll
                for (int j=0;j<6;j++)
                    acc[i][j] = MFMA16(af[i], bf[j], acc[i][j]);
            __builtin_amdgcn_s_setprio(0);
        }
    }
#undef STAGE

    #pragma unroll
    for (int j=0;j<6;j++){
        int c = col0 + wc + j*16 + lr;         // 0..1535
        int head = c >> 7, rr = c & 127;
        int gcol = head*384 + rr;
        float gg = g[gcol], bv = bb[gcol];
        signed char* dst = (rr < 64) ? Qi : Ki;
        int dcol = rr & 63;
        #pragma unroll
        for (int i=0;i<4;i++){
            #pragma unroll
            for (int r=0;r<4;r++){
                int grow = row0 + wr + i*16 + lg*4 + r;
                float h = __fadd_rn(__fmul_rn(acc[i][j][r], gg), bv);
                int iv = (int)rintf(q8f(h)*8.0f);     // q4 value x8: exact int8
                int bq = grow >> 10, n = grow & 1023;
                dst[((size_t)(bq*NH + head)*SEQ + n)*64 + dcol] = (signed char)iv;
            }
        }
    }
}

// ---------------- K2: pass A — int8 MFMA bias-free max/second-max screen ----
__global__ __launch_bounds__(256) void pass_a(
    const signed char* __restrict__ Qi, const signed char* __restrict__ Ki,
    const float* __restrict__ Bh,
    int* __restrict__ cnt2, int2* __restrict__ amb)
{
    __shared__ signed char Ks[128][64];

    const int t = threadIdx.x;
    const int bid = blockIdx.x;                 // 0..1535
    const int wg  = (bid & 7)*192 + (bid >> 3);
    const int bh  = wg >> 4;
    const int qt  = wg & 15;
    const int n0 = qt*64;
    const int lane = t&63, w = t>>6;
    const int lr = lane&15, lg = lane>>4;

    const float thr512 = (THR_NOT + 2.0f*Bh[bh % NH] + 1e-4f) * 512.0f;

    const signed char* qp = Qi + ((size_t)bh*SEQ + n0 + w*16 + lr)*64;
    const i32x4 aq = *(const i32x4*)(qp + lg*16);

    const signed char* Kb = Ki + (size_t)bh*SEQ*64;

    int mx[4], m2[4];
    #pragma unroll
    for (int r=0;r<4;r++){ mx[r] = -(1<<30); m2[r] = -(1<<30); }

    for (int kb = 0; kb < SEQ; kb += 128){
        __syncthreads();
        for (int s = t; s < 512; s += 256){
            int r = s>>2, gsw = s&3;
            int src = (gsw ^ (r&3))*16;           // both-sides swizzle
            *(i32x4*)&Ks[r][gsw*16] = *(const i32x4*)(Kb + (size_t)(kb + r)*64 + src);
        }
        __syncthreads();
        #pragma unroll
        for (int ct=0; ct<8; ct++){
            const int row = ct*16 + lr;
            i32x4 bq = *(const i32x4*)&Ks[row][(lg ^ (lr&3))*16];
            i32x4 c = {0,0,0,0};
            c = MFMAI8(aq, bq, c);
            #pragma unroll
            for (int r=0;r<4;r++){
                int sc = c[r];
                int om = mx[r];
                // m2' = median(sc, m2, mx_old); mx' = max(mx_old, sc)  -- 2 VALU ops
                asm("v_med3_i32 %0, %1, %2, %3" : "=v"(m2[r]) : "v"(sc), "v"(m2[r]), "v"(om));
                mx[r] = max(om, sc);
            }
        }
    }

    #pragma unroll
    for (int r=0;r<4;r++){
        int mxv = mx[r], m2v = m2[r];
        #pragma unroll
        for (int d=1; d<16; d<<=1){
            int mo  = __shfl_xor(mxv, d);
            int m2o = __shfl_xor(m2v, d);
            int sec = max(min(mxv, mo), (mxv >= mo) ? m2v : m2o);
            mxv = max(mxv, mo);
            m2v = sec;
        }
        if (lr == 0){
            if ((float)(m2v - mxv) < thr512){
                int n = n0 + w*16 + lg*4 + r;
                int pos = atomicAdd(cnt2, 1);
                if (pos < ECAP) amb[pos] = make_int2((bh<<10) | n, 0);
            }
        }
    }
}

// ---------------- K3: merged tail — exact resolve + rare-path correction ----
__global__ __launch_bounds__(256) void tail_kernel(
    const signed char* __restrict__ Qi, const signed char* __restrict__ Ki,
    const float* __restrict__ biases, int NU,
    const f16* __restrict__ xq, const f16* __restrict__ wqk,
    const float* __restrict__ qkv_w,
    const float* __restrict__ g, const float* __restrict__ bb,
    const float* __restrict__ proj_w, const float* __restrict__ pg,
    const int* __restrict__ cnt2, const int2* __restrict__ amb,
    float* __restrict__ out)
{
    __shared__ int   qr[64];
    __shared__ float rmax[4], rsum[4];
    __shared__ int   rarg[4];
    __shared__ float xr_n[768], xr_m[768];
    __shared__ float qs[64], ks[64];
    __shared__ float hq[256];
    __shared__ float s_as;
    __shared__ int   s_ms, s_flag;
    int total = *cnt2; if (total > ECAP) total = ECAP;
    const int t = threadIdx.x;
    for (int e = blockIdx.x; e < total; e += gridDim.x){
        int2 a = amb[e];
        int bh = a.x>>10, n = a.x&1023;
        int h = bh % NH, b = bh / NH;
        __syncthreads();
        if (t < 64) qr[t] = (int)Qi[((size_t)bh*SEQ + n)*64 + t];
        __syncthreads();

        // ---- exact biased resolve (int dot, bit-identical to reference) ----
        int rn = n>>5, cnn = n&31;
        float lmax = -3e38f; int larg = 0; float lsc[4];
        #pragma unroll
        for (int j=0;j<4;j++){
            int m = t + j*256;
            const signed char* kp = &Ki[((size_t)bh*SEQ + m)*64];
            int d = 0;
            for (int u=0; u<64; u++) d += qr[u]*(int)kp[u];
            int idx = __builtin_abs(rn-(m>>5))*32 + __builtin_abs(cnn-(m&31));
            lsc[j] = (float)d*(1.0f/512.0f) + biases[h*NU + idx];
            if (lsc[j] > lmax){ lmax = lsc[j]; larg = m; }
        }
        #pragma unroll
        for (int dd=32; dd>=1; dd>>=1){
            float mo = __shfl_xor(lmax, dd);
            int   ao = __shfl_xor(larg, dd);
            if (mo > lmax){ lmax = mo; larg = ao; }
        }
        if ((t&63)==0){ rmax[t>>6] = lmax; rarg[t>>6] = larg; }
        __syncthreads();
        float MX = rmax[0]; int ARG = rarg[0];
        #pragma unroll
        for (int k=1;k<4;k++){ if (rmax[k] > MX){ MX = rmax[k]; ARG = rarg[k]; } }
        float ls = 0.f;
        #pragma unroll
        for (int j=0;j<4;j++) ls += expf(lsc[j]-MX);
        #pragma unroll
        for (int dd=32; dd>=1; dd>>=1) ls += __shfl_xor(ls, dd);
        if ((t&63)==0) rsum[t>>6] = ls;
        __syncthreads();
        if (t==0){
            float SUM = rsum[0]+rsum[1]+rsum[2]+rsum[3];
            s_flag = (1.0f/SUM > 0.99f);
            s_ms = ARG;
        }
        __syncthreads();
        if (!s_flag) continue;
        const int ms = s_ms;

        // ---- correction: recompute q,k,v at q8 precision ----
        for (int i=t; i<768; i+=256){
            xr_n[i] = (float)xq[((size_t)b*SEQ + n)*768 + i];
            xr_m[i] = (float)xq[((size_t)b*SEQ + ms)*768 + i];
        }
        __syncthreads();
        if (t < 128){
            int col = t & 63;
            int qkr  = h*128 + (t<64 ? col : 64+col);
            int gcol = h*384 + (t<64 ? col : 64+col);
            const f16* wr = &wqk[(size_t)qkr*768];
            const float* xr = (t<64) ? xr_n : xr_m;
            float acc = 0.f;
            for (int d=0; d<768; d++) acc = fmaf(xr[d], (float)wr[d], acc);
            float hv = __fadd_rn(__fmul_rn(acc, g[gcol]), bb[gcol]);
            float v = q8f(hv);
            if (t<64) qs[col] = v; else ks[col] = v;
        }
        __syncthreads();
        if (t < 64){
            float p = qs[t]*ks[t];
            #pragma unroll
            for (int d=32; d>=1; d>>=1) p += __shfl_xor(p, d);
            if (t == 0){
                int idx = __builtin_abs((n>>5)-(ms>>5))*32 + __builtin_abs((n&31)-(ms&31));
                float ss = __fadd_rn(__fmul_rn(p, 0.125f), biases[h*NU + idx]);
                float mx2 = fmaxf(ss, 0.f);
                float es = expf(ss-mx2), e0 = expf(-mx2);
                float Z = fmaf(1023.f, e0, es);
                s_as = q8f(es/Z);     // off-argmax weights quantize to exactly 0
            }
        }
        __syncthreads();
        {
            int gcol = h*384 + 128 + t;
            const float* wr = &qkv_w[(size_t)gcol*768];   // quantize V weights on the fly
            float acc = 0.f;
            for (int d=0; d<768; d++) acc = fmaf(xr_m[d], q8f(wr[d]), acc);
            float hv = __fadd_rn(__fmul_rn(acc, g[gcol]), bb[gcol]);
            float vq = q8f(hv);
            float o = __fmul_rn(s_as, vq);
            float c6 = fminf(fmaxf(o+3.f, 0.f), 6.f);
            hq[t] = q8f(__fdiv_rn(__fmul_rn(o, c6), 6.f));
        }
        __syncthreads();
        #pragma unroll
        for (int cc=0; cc<3; cc++){
            int c = t + cc*256;
            float s = 0.f;
            for (int d=0; d<256; d++)
                s = fmaf(hq[d], q8f(proj_w[(size_t)c*3072 + h*256 + d]), s);
            atomicAdd(&out[((size_t)b*SEQ + n)*768 + c], __fmul_rn(pg[c], s));
        }
    }
}

extern "C" void kernel_launch(void* const* d_in, const int* in_sizes, int n_in,
                              void* d_out, int out_size, void* d_ws, size_t ws_size,
                              hipStream_t stream)
{
    const float* x       = (const float*)d_in[0];
    const float* qkv_w   = (const float*)d_in[1];
    const float* qkv_g   = (const float*)d_in[2];
    const float* qkv_b   = (const float*)d_in[3];
    const float* proj_w  = (const float*)d_in[4];
    const float* proj_g  = (const float*)d_in[5];
    const float* proj_b  = (const float*)d_in[6];
    const float* biases  = (const float*)d_in[7];
    const int NU = in_sizes[7] / NH;   // 1024

    char* w = (char*)d_ws;
    f16* xq  = (f16*)w; w += (size_t)8192*768*2;
    f16* wqk = (f16*)w; w += (size_t)1536*768*2;
    signed char* Qi = (signed char*)w; w += (size_t)96*1024*64;
    signed char* Ki = (signed char*)w; w += (size_t)96*1024*64;
    int* cnt2= (int*)w;  w += 16;
    float* Bh = (float*)w; w += 64;
    int2* amb = (int2*)w; w += (size_t)ECAP*8;

    prelude<<<13452, 256, 0, stream>>>(x, qkv_w, (float*)d_out, proj_b, biases, NU,
                                       xq, wqk, Bh, cnt2);

    gemm_qk<<<512, 256, 0, stream>>>(xq, wqk, qkv_g, qkv_b, Qi, Ki);

    pass_a<<<1536, 256, 0, stream>>>(Qi, Ki, Bh, cnt2, amb);

    tail_kernel<<<256, 256, 0, stream>>>(Qi, Ki, biases, NU, xq, wqk, qkv_w,
                                         qkv_g, qkv_b, proj_w, proj_g,
                                         cnt2, amb, (float*)d_out);
}